// Round 5
// baseline (454.939 us; speedup 1.0000x reference)
//
#include <hip/hip_runtime.h>

#define NN 32      // nodes
#define FF 64      // GAT out features
#define HH 128     // LSTM hidden
#define G4 512     // 4*H
#define BB 32      // batch
#define TT 512     // time steps
#define ET 128     // 96 edges + 32 self loops
#define NPOS (BB*TT)

__device__ __forceinline__ float frcp(float x) { return __builtin_amdgcn_rcpf(x); }

// ---------------- prep: fold GAT linear into LSTM input weights + Wt transpose ----------------
// R17 weight layout (1024-thread lstm): thread tid = r*8 + q (r=0..127 row, q=0..7 k-eighth).
// Per thread 64 weights, j = n*16 + p*8 + g*2 + e (chunk n=0..3, pair p, gate g, elem e):
//   Wt[tid*64 + j] = W_hh[(q*16 + 4*n + 2*p + e)][g*128 + r]
__global__ __launch_bounds__(512) void prep_kernel(const float* __restrict__ w_gat,
                                                   const float* __restrict__ b_gat,
                                                   const float* __restrict__ W_ih,
                                                   const float* __restrict__ W_hh,
                                                   float* __restrict__ W_eff,
                                                   float* __restrict__ biasp,
                                                   float* __restrict__ Wt) {
  int j = threadIdx.x;
  int n = blockIdx.x;
  float accw = 0.f, accb = 0.f;
#pragma unroll 8
  for (int f = 0; f < FF; ++f) {
    float wv = W_ih[(n * FF + f) * G4 + j];
    accw = fmaf(w_gat[f], wv, accw);
    accb = fmaf(b_gat[f], wv, accb);
  }
  W_eff[n * G4 + j] = accw;
  biasp[n * G4 + j] = accb;
  int g0 = (n * G4 + j) * 4;
#pragma unroll
  for (int qq = 0; qq < 4; ++qq) {
    int E = g0 + qq;
    int tl = E >> 6;          // lstm thread 0..1023
    int idx = E & 63;         // weight j
    int cn = idx >> 4;        // chunk 0..3
    int p = (idx >> 3) & 1;   // pair
    int g = (idx >> 1) & 3;   // gate
    int e = idx & 1;
    int r = tl >> 3, q = tl & 7;
    int k = q * 16 + 4 * cn + 2 * p + e;
    Wt[E] = W_hh[k * G4 + g * 128 + r];
  }
}

// ---------------- fused GAT + xw (+ block-local bias/sort/scal) ----------------
__global__ __launch_bounds__(256) void gatxw_kernel(const float* __restrict__ x_seq,
                                                    const int* __restrict__ ei,
                                                    const float* __restrict__ w_gat,
                                                    const float* __restrict__ att_src,
                                                    const float* __restrict__ att_dst,
                                                    const float* __restrict__ b_ih,
                                                    const float* __restrict__ b_hh,
                                                    const float* __restrict__ W_eff,
                                                    const float* __restrict__ biasp,
                                                    float* __restrict__ xw) {
  __shared__ int srt[ET];
  __shared__ int offs[NN + 1];
  __shared__ int cnt[NN];
  __shared__ float xs[256];
  __shared__ float sl[256];
  __shared__ float scal_sh[2];
  int tid = threadIdx.x;
  int posbase = blockIdx.x * 8;
  float we0[NN], we1[NN];
#pragma unroll
  for (int nn = 0; nn < NN; ++nn) {
    we0[nn] = W_eff[nn * G4 + tid];
    we1[nn] = W_eff[nn * G4 + 256 + tid];
  }
  float b0 = b_ih[tid] + b_hh[tid];
  float b1 = b_ih[256 + tid] + b_hh[256 + tid];
#pragma unroll 8
  for (int n = 0; n < NN; ++n) {
    b0 += biasp[n * G4 + tid];
    b1 += biasp[n * G4 + 256 + tid];
  }
  if (tid < NN) cnt[tid] = 0;
  __syncthreads();
  int es = 0, ed = 0, tk = 0;
  if (tid < ET) {
    if (tid < 96) { es = ei[tid]; ed = ei[96 + tid]; }
    else { es = tid - 96; ed = tid - 96; }
    tk = atomicAdd(&cnt[ed], 1);
  }
  __syncthreads();
  if (tid == 0) {
    offs[0] = 0;
    for (int n = 0; n < NN; ++n) offs[n + 1] = offs[n] + cnt[n];
  }
  if (tid == 1) {
    float cs = 0.f, cd = 0.f;
    for (int f = 0; f < FF; ++f) {
      cs = fmaf(w_gat[f], att_src[f], cs);
      cd = fmaf(w_gat[f], att_dst[f], cd);
    }
    scal_sh[0] = cs;
    scal_sh[1] = cd;
  }
  __syncthreads();
  if (tid < ET) srt[offs[ed] + tk] = es;
  xs[tid] = x_seq[posbase * NN + tid];  // coalesced
  __syncthreads();
  float cs = scal_sh[0], cd = scal_sh[1];
  int p = tid >> 5, n = tid & 31;
  int base = p * 32;
  int e0 = offs[n], e1 = offs[n + 1];
  float xn = xs[base + n];
  float cdxn = cd * xn;
  float m = -3.0e38f;
  for (int e = e0; e < e1; ++e) {
    float ev = fmaf(cs, xs[base + srt[e]], cdxn);
    ev = ev > 0.f ? ev : 0.2f * ev;  // LeakyReLU(0.2)
    m = fmaxf(m, ev);
  }
  float z = 0.f, sa = 0.f;
  for (int e = e0; e < e1; ++e) {
    float xsv = xs[base + srt[e]];
    float ev = fmaf(cs, xsv, cdxn);
    ev = ev > 0.f ? ev : 0.2f * ev;
    float ex = __expf(ev - m);
    z += ex;
    sa = fmaf(ex, xsv, sa);
  }
  sl[p * 32 + n] = sa * frcp(z);
  __syncthreads();
  for (int pp = 0; pp < 8; ++pp) {
    const float4* sp = (const float4*)&sl[pp * 32];
    float a0 = b0, a1 = b1;
#pragma unroll
    for (int q = 0; q < 8; ++q) {
      float4 sv = sp[q];
      a0 = fmaf(sv.x, we0[4 * q], a0);
      a0 = fmaf(sv.y, we0[4 * q + 1], a0);
      a0 = fmaf(sv.z, we0[4 * q + 2], a0);
      a0 = fmaf(sv.w, we0[4 * q + 3], a0);
      a1 = fmaf(sv.x, we1[4 * q], a1);
      a1 = fmaf(sv.y, we1[4 * q + 1], a1);
      a1 = fmaf(sv.z, we1[4 * q + 2], a1);
      a1 = fmaf(sv.w, we1[4 * q + 3], a1);
    }
    size_t row = (size_t)(posbase + pp) * G4;
    xw[row + tid] = a0;
    xw[row + 256 + tid] = a1;
  }
}

// ---------------- LSTM scan: R17 — 1024 threads, 4 waves/SIMD for latency hiding ----------------
// R13/R15/R16 established: LDS traffic is NOT the bottleneck (broadcast reads dedup; cutting
// 64->16 reads didn't help). R13's 1267cy/step = ~700cy VALU issue (2 waves/SIMD) + ~550cy
// latency (post-barrier ds_read ~120cy, serial act tail ~130cy, barrier resync) with only
// 2 waves/SIMD to hide it. R17: 16 waves (4/SIMD). Thread (r,q): q=0..7 k-eighths,
// 32 pk_fma + 4 ds_read_b128; 8-lane reduce = XOR1,XOR2 quad_perm + row_half_mirror
// (valid as XOR4: values quad-uniform after 2 rounds). VGPR engineered to 128 exactly.
//
// Reg map: v32-39 h (ping-pong, reads reuse) | v40-103 weights | v104-111 acc pairs
// v112-119 tail temps | v120 c | v121/122 x ring | v123 xaddr | v124 rd | v125 wr
// v126 Af | v127 Bf

#define PK4F(HP, W0, W1, W2, W3) \
  "v_pk_fma_f32 v[104:105], v[" HP "], v[" W0 "], 0\n\t" \
  "v_pk_fma_f32 v[106:107], v[" HP "], v[" W1 "], 0\n\t" \
  "v_pk_fma_f32 v[108:109], v[" HP "], v[" W2 "], 0\n\t" \
  "v_pk_fma_f32 v[110:111], v[" HP "], v[" W3 "], 0\n\t"

#define PK4A(HP, W0, W1, W2, W3) \
  "v_pk_fma_f32 v[104:105], v[" HP "], v[" W0 "], v[104:105]\n\t" \
  "v_pk_fma_f32 v[106:107], v[" HP "], v[" W1 "], v[106:107]\n\t" \
  "v_pk_fma_f32 v[108:109], v[" HP "], v[" W2 "], v[108:109]\n\t" \
  "v_pk_fma_f32 v[110:111], v[" HP "], v[" W3 "], v[110:111]\n\t"

// one time step: read h (4xb128, ping-pong regs), 32 pk_fma, 8-lane reduce,
// gate-split activation, c update, tanh, write h
#define PHASE(XSLOT, O0, O1, O2, O3, WOFF) \
  "ds_read_b128 v[32:35], v124 offset:" O0 "\n\t" \
  "ds_read_b128 v[36:39], v124 offset:" O1 "\n\t" \
  "s_waitcnt lgkmcnt(1)\n\t" \
  PK4F("32:33", "40:41", "42:43", "44:45", "46:47") \
  PK4A("34:35", "48:49", "50:51", "52:53", "54:55") \
  "ds_read_b128 v[32:35], v124 offset:" O2 "\n\t" \
  "s_waitcnt lgkmcnt(1)\n\t" \
  PK4A("36:37", "56:57", "58:59", "60:61", "62:63") \
  PK4A("38:39", "64:65", "66:67", "68:69", "70:71") \
  "ds_read_b128 v[36:39], v124 offset:" O3 "\n\t" \
  "s_waitcnt lgkmcnt(1)\n\t" \
  PK4A("32:33", "72:73", "74:75", "76:77", "78:79") \
  PK4A("34:35", "80:81", "82:83", "84:85", "86:87") \
  "s_waitcnt lgkmcnt(0)\n\t" \
  PK4A("36:37", "88:89", "90:91", "92:93", "94:95") \
  PK4A("38:39", "96:97", "98:99", "100:101", "102:103") \
  "v_add_f32 v112, v104, v105\n\t" \
  "v_add_f32 v113, v106, v107\n\t" \
  "v_add_f32 v114, v108, v109\n\t" \
  "v_add_f32 v115, v110, v111\n\t" \
  "v_add_f32_dpp v112, v112, v112 quad_perm:[1,0,3,2] row_mask:0xf bank_mask:0xf\n\t" \
  "v_add_f32_dpp v113, v113, v113 quad_perm:[1,0,3,2] row_mask:0xf bank_mask:0xf\n\t" \
  "v_add_f32_dpp v114, v114, v114 quad_perm:[1,0,3,2] row_mask:0xf bank_mask:0xf\n\t" \
  "v_add_f32_dpp v115, v115, v115 quad_perm:[1,0,3,2] row_mask:0xf bank_mask:0xf\n\t" \
  "v_add_f32_dpp v112, v112, v112 quad_perm:[2,3,0,1] row_mask:0xf bank_mask:0xf\n\t" \
  "v_add_f32_dpp v113, v113, v113 quad_perm:[2,3,0,1] row_mask:0xf bank_mask:0xf\n\t" \
  "v_add_f32_dpp v114, v114, v114 quad_perm:[2,3,0,1] row_mask:0xf bank_mask:0xf\n\t" \
  "v_add_f32_dpp v115, v115, v115 quad_perm:[2,3,0,1] row_mask:0xf bank_mask:0xf\n\t" \
  "v_add_f32_dpp v112, v112, v112 row_half_mirror row_mask:0xf bank_mask:0xf\n\t" \
  "v_add_f32_dpp v113, v113, v113 row_half_mirror row_mask:0xf bank_mask:0xf\n\t" \
  "v_add_f32_dpp v114, v114, v114 row_half_mirror row_mask:0xf bank_mask:0xf\n\t" \
  "v_add_f32_dpp v115, v115, v115 row_half_mirror row_mask:0xf bank_mask:0xf\n\t" \
  "v_cndmask_b32 v116, v112, v113, s[22:23]\n\t" \
  "v_cndmask_b32 v117, v114, v115, s[22:23]\n\t" \
  "v_cndmask_b32 v116, v116, v117, s[24:25]\n\t" \
  "s_waitcnt vmcnt(1)\n\t" \
  "v_add_f32 v116, v116, " XSLOT "\n\t" \
  "global_load_dword " XSLOT ", v123, %[xwb]\n\t" \
  "v_add_u32 v123, 0x800, v123\n\t" \
  "v_mul_f32 v117, 0xbfb8aa3b, v116\n\t" \
  "v_mul_f32 v117, v126, v117\n\t" \
  "v_exp_f32 v117, v117\n\t" \
  "s_nop 0\n\t" \
  "v_add_f32 v117, 1.0, v117\n\t" \
  "v_rcp_f32 v117, v117\n\t" \
  "s_nop 0\n\t" \
  "v_fma_f32 v118, v126, v117, v127\n\t" \
  "s_nop 1\n\t" \
  "v_mov_b32_dpp v112, v118 quad_perm:[0,0,0,0] row_mask:0xf bank_mask:0xf\n\t" \
  "v_mov_b32_dpp v113, v118 quad_perm:[1,1,1,1] row_mask:0xf bank_mask:0xf\n\t" \
  "v_mov_b32_dpp v114, v118 quad_perm:[2,2,2,2] row_mask:0xf bank_mask:0xf\n\t" \
  "v_mov_b32_dpp v115, v118 quad_perm:[3,3,3,3] row_mask:0xf bank_mask:0xf\n\t" \
  "v_mul_f32 v112, v112, v114\n\t" \
  "v_fma_f32 v120, v113, v120, v112\n\t" \
  "v_mul_f32 v117, 0x4038aa3b, v120\n\t" \
  "v_exp_f32 v117, v117\n\t" \
  "s_nop 0\n\t" \
  "v_add_f32 v117, 1.0, v117\n\t" \
  "v_rcp_f32 v117, v117\n\t" \
  "s_nop 0\n\t" \
  "v_fma_f32 v117, -2.0, v117, 1.0\n\t" \
  "v_mul_f32 v118, v115, v117\n\t" \
  "ds_write_b32 v125, v118 offset:" WOFF "\n\t" \
  "s_waitcnt lgkmcnt(0)\n\t" \
  "s_barrier\n\t"

__global__ __launch_bounds__(1024, 4) void lstm_kernel(const float* __restrict__ xw,
                                                       const float* __restrict__ Wt,
                                                       const float* __restrict__ W_fc,
                                                       const float* __restrict__ b_fc,
                                                       float* __restrict__ out) {
  __shared__ __align__(16) float lds[256];  // hA [0,128) floats, hB [128,256), linear h[k]
  int b = blockIdx.x, tid = threadIdx.x;
  int r = tid >> 3, q = tid & 7;
  int gq = q & 3;
  if (tid < 256) lds[tid] = 0.f;
  const float* xwb = xw + (size_t)b * TT * G4;
  unsigned xoff0 = (unsigned)((gq * 128 + r) * 4);  // t=0
  unsigned wtoff = (unsigned)(tid * 256);           // 64 floats per thread
  unsigned lbase = (unsigned)(uintptr_t)&lds[0];    // LDS aperture is 4GB-aligned
  unsigned rd = lbase + (unsigned)(q * 64);         // h floats [q*16, q*16+16); B at +512
  unsigned wr = lbase + (unsigned)(r * 4);          // h[r], 8-way same-addr write; B at +512
  // gate-split act constants: lane gq handles gate gq (i,f,o sigmoid; g=2 tanh)
  // exp arg = A * (-log2e) * z; out = A*rcp + B
  float Af = (gq == 2) ? -2.f : 1.f;
  float Bf = (gq == 2) ? 1.f : 0.f;
  unsigned qodd = q & 1, qhi = (q >> 1) & 1;
  __syncthreads();
  asm volatile(
    "v_mov_b32 v123, %[xo]\n\t"
    "v_mov_b32 v124, %[rd]\n\t"
    "v_mov_b32 v125, %[wr]\n\t"
    "v_mov_b32 v126, %[Aa]\n\t"
    "v_mov_b32 v127, %[Bb]\n\t"
    "v_mov_b32 v120, 0\n\t"          // c
    "v_cmp_eq_u32 s[22:23], 1, %[qodd]\n\t"
    "v_cmp_eq_u32 s[24:25], 1, %[qhi]\n\t"
    // x prefetch ring (depth 2): t=0 -> v121, t=1 -> v122
    "global_load_dword v121, v123, %[xwb]\n\t"
    "v_add_u32 v123, 0x800, v123\n\t"
    "global_load_dword v122, v123, %[xwb]\n\t"
    "v_add_u32 v123, 0x800, v123\n\t"
    // 64 weights -> v40..v103
    "global_load_dwordx4 v[40:43], %[wto], %[wtb] offset:0\n\t"
    "global_load_dwordx4 v[44:47], %[wto], %[wtb] offset:16\n\t"
    "global_load_dwordx4 v[48:51], %[wto], %[wtb] offset:32\n\t"
    "global_load_dwordx4 v[52:55], %[wto], %[wtb] offset:48\n\t"
    "global_load_dwordx4 v[56:59], %[wto], %[wtb] offset:64\n\t"
    "global_load_dwordx4 v[60:63], %[wto], %[wtb] offset:80\n\t"
    "global_load_dwordx4 v[64:67], %[wto], %[wtb] offset:96\n\t"
    "global_load_dwordx4 v[68:71], %[wto], %[wtb] offset:112\n\t"
    "global_load_dwordx4 v[72:75], %[wto], %[wtb] offset:128\n\t"
    "global_load_dwordx4 v[76:79], %[wto], %[wtb] offset:144\n\t"
    "global_load_dwordx4 v[80:83], %[wto], %[wtb] offset:160\n\t"
    "global_load_dwordx4 v[84:87], %[wto], %[wtb] offset:176\n\t"
    "global_load_dwordx4 v[88:91], %[wto], %[wtb] offset:192\n\t"
    "global_load_dwordx4 v[92:95], %[wto], %[wtb] offset:208\n\t"
    "global_load_dwordx4 v[96:99], %[wto], %[wtb] offset:224\n\t"
    "global_load_dwordx4 v[100:103], %[wto], %[wtb] offset:240\n\t"
    "s_waitcnt vmcnt(0)\n\t"
    "s_movk_i32 s20, 0x100\n\t"    // 256 iterations x 2 phases = 512 steps
    "L_lstm_%=:\n\t"
    PHASE("v121", "0",   "16",  "32",  "48",  "512")   // t even: read A, write B
    PHASE("v122", "512", "528", "544", "560", "0")     // t odd:  read B, write A
    "s_sub_u32 s20, s20, 1\n\t"
    "s_cmp_lg_u32 s20, 0\n\t"
    "s_cbranch_scc1 L_lstm_%=\n\t"
    "s_waitcnt vmcnt(0) lgkmcnt(0)\n\t"
    :
    : [xwb]"s"(xwb), [wtb]"s"(Wt), [wto]"v"(wtoff), [xo]"v"(xoff0),
      [rd]"v"(rd), [wr]"v"(wr),
      [Aa]"v"(Af), [Bb]"v"(Bf),
      [qodd]"v"(qodd), [qhi]"v"(qhi)
    : "memory", "scc", "s20", "s22", "s23", "s24", "s25",
      "v32","v33","v34","v35","v36","v37","v38","v39",
      "v40","v41","v42","v43","v44","v45","v46","v47",
      "v48","v49","v50","v51","v52","v53","v54","v55",
      "v56","v57","v58","v59","v60","v61","v62","v63",
      "v64","v65","v66","v67","v68","v69","v70","v71",
      "v72","v73","v74","v75","v76","v77","v78","v79",
      "v80","v81","v82","v83","v84","v85","v86","v87",
      "v88","v89","v90","v91","v92","v93","v94","v95",
      "v96","v97","v98","v99","v100","v101","v102","v103",
      "v104","v105","v106","v107","v108","v109","v110","v111",
      "v112","v113","v114","v115","v116","v117","v118","v119",
      "v120","v121","v122","v123","v124","v125","v126","v127");
  __syncthreads();
  // final h (after t=511, odd -> buffer A) is linear: lds[k]
  if (tid < 4) {
    float acc = b_fc[tid];
#pragma unroll 8
    for (int k = 0; k < HH; ++k)
      acc = fmaf(lds[k], W_fc[k * 4 + tid], acc);
    out[b * 4 + tid] = acc;
  }
}

extern "C" void kernel_launch(void* const* d_in, const int* in_sizes, int n_in,
                              void* d_out, int out_size, void* d_ws, size_t ws_size,
                              hipStream_t stream) {
  const float* x_seq   = (const float*)d_in[0];
  const int*   ei      = (const int*)d_in[1];
  const float* w_gat   = (const float*)d_in[2];
  const float* att_src = (const float*)d_in[3];
  const float* att_dst = (const float*)d_in[4];
  const float* b_gat   = (const float*)d_in[5];
  const float* W_ih    = (const float*)d_in[6];
  const float* W_hh    = (const float*)d_in[7];
  const float* b_ih    = (const float*)d_in[8];
  const float* b_hh    = (const float*)d_in[9];
  const float* W_fc    = (const float*)d_in[10];
  const float* b_fc    = (const float*)d_in[11];

  float* ws = (float*)d_ws;
  float* Wt    = ws;                            // 1024*64 = 65536 f (16B-aligned)
  float* xw    = Wt + 65536;                    // (16384+8)*512 f (pad rows: prefetch overrun)
  float* W_eff = xw + (size_t)(NPOS + 8) * G4;  // 32*512
  float* biasp = W_eff + NN * G4;               // 32*512

  prep_kernel<<<NN, G4, 0, stream>>>(w_gat, b_gat, W_ih, W_hh, W_eff, biasp, Wt);
  gatxw_kernel<<<NPOS / 8, 256, 0, stream>>>(x_seq, ei, w_gat, att_src, att_dst,
                                             b_ih, b_hh, W_eff, biasp, xw);
  lstm_kernel<<<BB, 1024, 0, stream>>>(xw, Wt, W_fc, b_fc, (float*)d_out);
}